// Round 1
// baseline (2258.390 us; speedup 1.0000x reference)
//
#include <hip/hip_runtime.h>

#define N_NODES 100000
#define N_EDGES 800000
#define DIM 64
#define BN_EPS 1e-5f

// ---------------------------------------------------------------------------
// Degree / normalization precompute
// ---------------------------------------------------------------------------
__global__ void k_init_deg(float* __restrict__ deg) {
    int i = blockIdx.x * blockDim.x + threadIdx.x;
    if (i < N_NODES) deg[i] = 1.0f;   // self loop
}

__global__ void k_accum_deg(const int* __restrict__ dst, float* __restrict__ deg) {
    int e = blockIdx.x * blockDim.x + threadIdx.x;
    if (e < N_EDGES) atomicAdd(&deg[dst[e]], 1.0f);
}

__global__ void k_finalize_dinv(float* __restrict__ deg) {
    int i = blockIdx.x * blockDim.x + threadIdx.x;
    if (i < N_NODES) deg[i] = rsqrtf(deg[i]);
}

// ---------------------------------------------------------------------------
// out[n,64] = act(in[n,64] @ W[64,64] + bias)   mode: 0=none, 1=tanh
// 16 rows per block; 16 threads per row, 4 output cols each (float4).
// W staged in LDS (16 KB), X tile staged in LDS (padded to kill bank conflicts).
// ---------------------------------------------------------------------------
__global__ __launch_bounds__(256) void k_gemm64(const float* __restrict__ in,
                                                const float* __restrict__ W,
                                                const float* __restrict__ bias,
                                                float* __restrict__ out,
                                                int n, int mode) {
    __shared__ float sW[64][64];
    __shared__ float sX[16][65];
    int tid = threadIdx.x;

    // stage W: 4096 floats = 1024 float4, 256 threads x 4
    for (int i = tid; i < 1024; i += 256)
        ((float4*)&sW[0][0])[i] = ((const float4*)W)[i];

    int row0 = blockIdx.x * 16;
    int rl = tid >> 4;       // local row 0..15
    int c4 = tid & 15;       // float4 column 0..15

    {
        int r = row0 + rl;
        float4 v = make_float4(0.f, 0.f, 0.f, 0.f);
        if (r < n) v = ((const float4*)(in + (size_t)r * DIM))[c4];
        sX[rl][c4 * 4 + 0] = v.x;
        sX[rl][c4 * 4 + 1] = v.y;
        sX[rl][c4 * 4 + 2] = v.z;
        sX[rl][c4 * 4 + 3] = v.w;
    }
    __syncthreads();

    int c0 = c4 * 4;
    float4 acc = make_float4(0.f, 0.f, 0.f, 0.f);
#pragma unroll
    for (int k = 0; k < 64; k++) {
        float xv = sX[rl][k];
        float4 w = *(const float4*)&sW[k][c0];
        acc.x += xv * w.x;
        acc.y += xv * w.y;
        acc.z += xv * w.z;
        acc.w += xv * w.w;
    }
    if (bias) {
        acc.x += bias[c0 + 0];
        acc.y += bias[c0 + 1];
        acc.z += bias[c0 + 2];
        acc.w += bias[c0 + 3];
    }
    if (mode == 1) {
        acc.x = tanhf(acc.x);
        acc.y = tanhf(acc.y);
        acc.z = tanhf(acc.z);
        acc.w = tanhf(acc.w);
    }
    int r = row0 + rl;
    if (r < n) ((float4*)(out + (size_t)r * DIM))[c4] = acc;
}

// ---------------------------------------------------------------------------
// out[i] = bias + t[i] * dinv[i]^2     (self-loop message + bias)
// one thread per float4: N*16 threads
// ---------------------------------------------------------------------------
__global__ __launch_bounds__(256) void k_agg_init(const float* __restrict__ t,
                                                  const float* __restrict__ dinv,
                                                  const float* __restrict__ bias,
                                                  float* __restrict__ out) {
    int idx = blockIdx.x * blockDim.x + threadIdx.x;
    if (idx >= N_NODES * 16) return;
    int i = idx >> 4;
    int c4 = idx & 15;
    float w = dinv[i];
    w = w * w;
    float4 v = ((const float4*)t)[idx];
    float4 b = ((const float4*)bias)[c4];
    float4 o;
    o.x = b.x + v.x * w;
    o.y = b.y + v.y * w;
    o.z = b.z + v.z * w;
    o.w = b.w + v.w * w;
    ((float4*)out)[idx] = o;
}

// ---------------------------------------------------------------------------
// edge scatter: out[dst] += t[src] * dinv[src]*dinv[dst]
// 16 threads per edge, one float4 gather + 4 scalar atomics each
// ---------------------------------------------------------------------------
__global__ __launch_bounds__(256) void k_agg_edges(const float* __restrict__ t,
                                                   const int* __restrict__ ei,
                                                   const float* __restrict__ dinv,
                                                   float* __restrict__ out) {
    int idx = blockIdx.x * blockDim.x + threadIdx.x;
    if (idx >= N_EDGES * 16) return;
    int e = idx >> 4;
    int c4 = idx & 15;
    int s = ei[e];
    int d = ei[N_EDGES + e];
    float w = dinv[s] * dinv[d];
    float4 v = ((const float4*)(t + (size_t)s * DIM))[c4];
    float* op = out + (size_t)d * DIM + c4 * 4;
    atomicAdd(op + 0, v.x * w);
    atomicAdd(op + 1, v.y * w);
    atomicAdd(op + 2, v.z * w);
    atomicAdd(op + 3, v.w * w);
}

// ---------------------------------------------------------------------------
// in-place h = relu((h - m) * (g * rsqrt(v + eps)) + b)
// ---------------------------------------------------------------------------
__global__ __launch_bounds__(256) void k_bn_relu(float* __restrict__ h,
                                                 const float* __restrict__ g,
                                                 const float* __restrict__ b,
                                                 const float* __restrict__ m,
                                                 const float* __restrict__ v) {
    int idx = blockIdx.x * blockDim.x + threadIdx.x;
    if (idx >= N_NODES * 16) return;
    int c0 = (idx & 15) * 4;
    float4 x = ((float4*)h)[idx];
    float4 o;
    o.x = fmaxf(0.f, (x.x - m[c0 + 0]) * (g[c0 + 0] * rsqrtf(v[c0 + 0] + BN_EPS)) + b[c0 + 0]);
    o.y = fmaxf(0.f, (x.y - m[c0 + 1]) * (g[c0 + 1] * rsqrtf(v[c0 + 1] + BN_EPS)) + b[c0 + 1]);
    o.z = fmaxf(0.f, (x.z - m[c0 + 2]) * (g[c0 + 2] * rsqrtf(v[c0 + 2] + BN_EPS)) + b[c0 + 2]);
    o.w = fmaxf(0.f, (x.w - m[c0 + 3]) * (g[c0 + 3] * rsqrtf(v[c0 + 3] + BN_EPS)) + b[c0 + 3]);
    ((float4*)h)[idx] = o;
}

// ---------------------------------------------------------------------------
extern "C" void kernel_launch(void* const* d_in, const int* in_sizes, int n_in,
                              void* d_out, int out_size, void* d_ws, size_t ws_size,
                              hipStream_t stream) {
    const float* x     = (const float*)d_in[0];
    const int*   ei    = (const int*)d_in[1];
    const float* W1    = (const float*)d_in[2];
    const float* b1    = (const float*)d_in[3];
    const float* W2    = (const float*)d_in[4];
    const float* b2    = (const float*)d_in[5];
    const float* W3    = (const float*)d_in[6];
    const float* b3    = (const float*)d_in[7];
    const float* bn1_g = (const float*)d_in[8];
    const float* bn1_b = (const float*)d_in[9];
    const float* bn1_m = (const float*)d_in[10];
    const float* bn1_v = (const float*)d_in[11];
    const float* bn2_g = (const float*)d_in[12];
    const float* bn2_b = (const float*)d_in[13];
    const float* bn2_m = (const float*)d_in[14];
    const float* bn2_v = (const float*)d_in[15];
    const float* pW1   = (const float*)d_in[16];
    const float* pb1   = (const float*)d_in[17];
    const float* pW2   = (const float*)d_in[18];
    const float* pb2   = (const float*)d_in[19];
    float* out = (float*)d_out;

    float* ws_f  = (float*)d_ws;
    float* dinv  = ws_f;                       // N floats
    float* bufA  = ws_f + N_NODES;             // N*64
    float* bufB  = bufA + (size_t)N_NODES * DIM;

    const int blk = 256;
    int gN    = (N_NODES + blk - 1) / blk;          // 391
    int gE    = (N_EDGES + blk - 1) / blk;          // 3125
    int gRows = (N_NODES + 15) / 16;                // 6250 (gemm + elementwise)
    int gEdg  = (N_EDGES * 16 + blk - 1) / blk;     // 50000

    // normalization coefficients
    k_init_deg<<<gN, blk, 0, stream>>>(dinv);
    k_accum_deg<<<gE, blk, 0, stream>>>(ei + N_EDGES, dinv);
    k_finalize_dinv<<<gN, blk, 0, stream>>>(dinv);

    // layer 1
    k_gemm64<<<gRows, blk, 0, stream>>>(x, W1, nullptr, bufA, N_NODES, 0);
    k_agg_init<<<gRows, blk, 0, stream>>>(bufA, dinv, b1, bufB);
    k_agg_edges<<<gEdg, blk, 0, stream>>>(bufA, ei, dinv, bufB);
    k_bn_relu<<<gRows, blk, 0, stream>>>(bufB, bn1_g, bn1_b, bn1_m, bn1_v);

    // layer 2
    k_gemm64<<<gRows, blk, 0, stream>>>(bufB, W2, nullptr, bufA, N_NODES, 0);
    k_agg_init<<<gRows, blk, 0, stream>>>(bufA, dinv, b2, bufB);
    k_agg_edges<<<gEdg, blk, 0, stream>>>(bufA, ei, dinv, bufB);
    k_bn_relu<<<gRows, blk, 0, stream>>>(bufB, bn2_g, bn2_b, bn2_m, bn2_v);

    // layer 3
    k_gemm64<<<gRows, blk, 0, stream>>>(bufB, W3, nullptr, bufA, N_NODES, 0);
    k_agg_init<<<gRows, blk, 0, stream>>>(bufA, dinv, b3, bufB);
    k_agg_edges<<<gEdg, blk, 0, stream>>>(bufA, ei, dinv, bufB);

    // predictor MLP
    k_gemm64<<<gRows, blk, 0, stream>>>(bufB, pW1, pb1, bufA, N_NODES, 1);
    k_gemm64<<<gRows, blk, 0, stream>>>(bufA, pW2, pb2, out, N_NODES, 0);
}

// Round 2
// 515.063 us; speedup vs baseline: 4.3847x; 4.3847x over previous
//
#include <hip/hip_runtime.h>

#define N_NODES 100000
#define N_EDGES 800000
#define DIM 64
#define BN_EPS 1e-5f

// ===========================================================================
// CSR build: count in-degrees, exclusive scan, scatter edges grouped by dst.
// Order within a node's segment is arbitrary (atomic cursor) — only changes
// float summation order, well within threshold.
// ===========================================================================

__global__ __launch_bounds__(256) void k_zero_deg(int* __restrict__ deg) {
    int i = blockIdx.x * blockDim.x + threadIdx.x;
    if (i < N_NODES) deg[i] = 0;
}

__global__ __launch_bounds__(256) void k_count(const int* __restrict__ dst,
                                               int* __restrict__ deg) {
    int e = blockIdx.x * blockDim.x + threadIdx.x;
    if (e < N_EDGES) atomicAdd(&deg[dst[e]], 1);
}

// 98 blocks x 256 threads x 4 elems = 100352 >= N. Per-block exclusive scan.
__global__ __launch_bounds__(256) void k_scan1(const int* __restrict__ deg,
                                               int* __restrict__ row_off,
                                               int* __restrict__ block_sums) {
    __shared__ int sdata[256];
    int tid = threadIdx.x;
    int base = blockIdx.x * 1024 + tid * 4;
    int4 v = make_int4(0, 0, 0, 0);
    if (base < N_NODES) v = *(const int4*)(deg + base);   // N % 4 == 0
    int tsum = v.x + v.y + v.z + v.w;
    sdata[tid] = tsum;
    __syncthreads();
    // Hillis-Steele inclusive scan
    for (int off = 1; off < 256; off <<= 1) {
        int t = (tid >= off) ? sdata[tid - off] : 0;
        __syncthreads();
        sdata[tid] += t;
        __syncthreads();
    }
    int excl = sdata[tid] - tsum;   // exclusive prefix within block
    if (base < N_NODES) {
        int4 o;
        o.x = excl;
        o.y = o.x + v.x;
        o.z = o.y + v.y;
        o.w = o.z + v.z;
        *(int4*)(row_off + base) = o;
    }
    if (tid == 255) block_sums[blockIdx.x] = sdata[255];
}

// single block scans the 98 block sums -> exclusive prefixes
__global__ __launch_bounds__(128) void k_scan2(int* __restrict__ block_sums) {
    __shared__ int sdata[128];
    int tid = threadIdx.x;
    int v = (tid < 98) ? block_sums[tid] : 0;
    sdata[tid] = v;
    __syncthreads();
    for (int off = 1; off < 128; off <<= 1) {
        int t = (tid >= off) ? sdata[tid - off] : 0;
        __syncthreads();
        sdata[tid] += t;
        __syncthreads();
    }
    if (tid < 98) block_sums[tid] = sdata[tid] - v;   // exclusive
}

// add block prefix; init cursor; compute dinv = rsqrt(deg+1)
__global__ __launch_bounds__(256) void k_scan3(const int* __restrict__ deg,
                                               int* __restrict__ row_off,
                                               int* __restrict__ cursor,
                                               float* __restrict__ dinv,
                                               const int* __restrict__ block_sums) {
    int tid = threadIdx.x;
    int base = blockIdx.x * 1024 + tid * 4;
    if (base >= N_NODES) return;
    int p = block_sums[blockIdx.x];
    int4 r = *(const int4*)(row_off + base);
    r.x += p; r.y += p; r.z += p; r.w += p;
    *(int4*)(row_off + base) = r;
    *(int4*)(cursor + base) = r;
    int4 d = *(const int4*)(deg + base);
    float4 di;
    di.x = rsqrtf((float)(d.x + 1));
    di.y = rsqrtf((float)(d.y + 1));
    di.z = rsqrtf((float)(d.z + 1));
    di.w = rsqrtf((float)(d.w + 1));
    *(float4*)(dinv + base) = di;
}

__global__ __launch_bounds__(256) void k_build(const int* __restrict__ ei,
                                               const float* __restrict__ dinv,
                                               int* __restrict__ cursor,
                                               int* __restrict__ csr_src,
                                               float* __restrict__ csr_w) {
    int e = blockIdx.x * blockDim.x + threadIdx.x;
    if (e >= N_EDGES) return;
    int s = ei[e];
    int d = ei[N_EDGES + e];
    int pos = atomicAdd(&cursor[d], 1);
    csr_src[pos] = s;
    csr_w[pos] = dinv[s] * dinv[d];
}

// ===========================================================================
// Aggregation: one 64-lane wave per node, lane = feature column.
// acc = dinv[n]^2 * x[n] + sum_e w_e * x[src_e]   — no atomics.
// Edge metadata loaded 64-at-a-time by lanes, broadcast via shfl.
// ===========================================================================
__global__ __launch_bounds__(256) void k_aggregate(const float* __restrict__ x,
                                                   const int* __restrict__ row_off,
                                                   const int* __restrict__ deg,
                                                   const int* __restrict__ csr_src,
                                                   const float* __restrict__ csr_w,
                                                   const float* __restrict__ dinv,
                                                   float* __restrict__ out) {
    int node = blockIdx.x * 4 + (threadIdx.x >> 6);
    if (node >= N_NODES) return;
    int lane = threadIdx.x & 63;
    float di = dinv[node];
    float acc = x[(size_t)node * DIM + lane] * di * di;
    int beg = row_off[node];
    int len = deg[node];
    for (int c = 0; c < len; c += 64) {
        int m = min(64, len - c);
        int sv = 0;
        float wv = 0.f;
        if (lane < m) {
            sv = csr_src[beg + c + lane];
            wv = csr_w[beg + c + lane];
        }
        for (int k = 0; k < m; ++k) {
            int ss = __shfl(sv, k);
            float ww = __shfl(wv, k);
            acc += ww * x[(size_t)ss * DIM + lane];
        }
    }
    out[(size_t)node * DIM + lane] = acc;
}

// ===========================================================================
// out[n,64] = epilogue(in[n,64] @ W[64,64] + bias)
// mode: 0 = none, 1 = tanh, 2 = BN+ReLU
// ===========================================================================
__global__ __launch_bounds__(256) void k_gemm64(const float* __restrict__ in,
                                                const float* __restrict__ W,
                                                const float* __restrict__ bias,
                                                const float* __restrict__ bng,
                                                const float* __restrict__ bnb,
                                                const float* __restrict__ bnm,
                                                const float* __restrict__ bnv,
                                                float* __restrict__ out,
                                                int n, int mode) {
    __shared__ float sW[64][64];
    __shared__ float sX[16][65];
    int tid = threadIdx.x;

    for (int i = tid; i < 1024; i += 256)
        ((float4*)&sW[0][0])[i] = ((const float4*)W)[i];

    int row0 = blockIdx.x * 16;
    int rl = tid >> 4;
    int c4 = tid & 15;

    {
        int r = row0 + rl;
        float4 v = make_float4(0.f, 0.f, 0.f, 0.f);
        if (r < n) v = ((const float4*)(in + (size_t)r * DIM))[c4];
        sX[rl][c4 * 4 + 0] = v.x;
        sX[rl][c4 * 4 + 1] = v.y;
        sX[rl][c4 * 4 + 2] = v.z;
        sX[rl][c4 * 4 + 3] = v.w;
    }
    __syncthreads();

    int c0 = c4 * 4;
    float4 acc = make_float4(0.f, 0.f, 0.f, 0.f);
#pragma unroll
    for (int k = 0; k < 64; k++) {
        float xv = sX[rl][k];
        float4 w = *(const float4*)&sW[k][c0];
        acc.x += xv * w.x;
        acc.y += xv * w.y;
        acc.z += xv * w.z;
        acc.w += xv * w.w;
    }
    acc.x += bias[c0 + 0];
    acc.y += bias[c0 + 1];
    acc.z += bias[c0 + 2];
    acc.w += bias[c0 + 3];
    if (mode == 1) {
        acc.x = tanhf(acc.x);
        acc.y = tanhf(acc.y);
        acc.z = tanhf(acc.z);
        acc.w = tanhf(acc.w);
    } else if (mode == 2) {
        float sx = bng[c0 + 0] * rsqrtf(bnv[c0 + 0] + BN_EPS);
        float sy = bng[c0 + 1] * rsqrtf(bnv[c0 + 1] + BN_EPS);
        float sz = bng[c0 + 2] * rsqrtf(bnv[c0 + 2] + BN_EPS);
        float sw = bng[c0 + 3] * rsqrtf(bnv[c0 + 3] + BN_EPS);
        acc.x = fmaxf(0.f, (acc.x - bnm[c0 + 0]) * sx + bnb[c0 + 0]);
        acc.y = fmaxf(0.f, (acc.y - bnm[c0 + 1]) * sy + bnb[c0 + 1]);
        acc.z = fmaxf(0.f, (acc.z - bnm[c0 + 2]) * sz + bnb[c0 + 2]);
        acc.w = fmaxf(0.f, (acc.w - bnm[c0 + 3]) * sw + bnb[c0 + 3]);
    }
    int r = row0 + rl;
    if (r < n) ((float4*)(out + (size_t)r * DIM))[c4] = acc;
}

// ===========================================================================
extern "C" void kernel_launch(void* const* d_in, const int* in_sizes, int n_in,
                              void* d_out, int out_size, void* d_ws, size_t ws_size,
                              hipStream_t stream) {
    const float* x     = (const float*)d_in[0];
    const int*   ei    = (const int*)d_in[1];
    const float* W1    = (const float*)d_in[2];
    const float* b1    = (const float*)d_in[3];
    const float* W2    = (const float*)d_in[4];
    const float* b2    = (const float*)d_in[5];
    const float* W3    = (const float*)d_in[6];
    const float* b3    = (const float*)d_in[7];
    const float* bn1_g = (const float*)d_in[8];
    const float* bn1_b = (const float*)d_in[9];
    const float* bn1_m = (const float*)d_in[10];
    const float* bn1_v = (const float*)d_in[11];
    const float* bn2_g = (const float*)d_in[12];
    const float* bn2_b = (const float*)d_in[13];
    const float* bn2_m = (const float*)d_in[14];
    const float* bn2_v = (const float*)d_in[15];
    const float* pW1   = (const float*)d_in[16];
    const float* pb1   = (const float*)d_in[17];
    const float* pW2   = (const float*)d_in[18];
    const float* pb2   = (const float*)d_in[19];
    float* out = (float*)d_out;

    // workspace layout (4-byte units)
    char* ws = (char*)d_ws;
    int*   deg      = (int*)ws;                      ws += 100352 * 4;
    int*   row_off  = (int*)ws;                      ws += 100352 * 4;
    int*   cursor   = (int*)ws;                      ws += 100352 * 4;
    int*   bsums    = (int*)ws;                      ws += 128 * 4;
    int*   csr_src  = (int*)ws;                      ws += N_EDGES * 4;
    float* csr_w    = (float*)ws;                    ws += N_EDGES * 4;
    float* dinv     = (float*)ws;                    ws += 100352 * 4;
    float* bufA     = (float*)ws;                    ws += (size_t)N_NODES * DIM * 4;
    float* bufB     = (float*)ws;

    const int blk = 256;
    int gN    = (N_NODES + blk - 1) / blk;       // 391
    int gE    = (N_EDGES + blk - 1) / blk;       // 3125
    int gScan = 98;                              // 98*1024 >= N
    int gAgg  = (N_NODES + 3) / 4;               // 25000
    int gRows = (N_NODES + 15) / 16;             // 6250

    // ---- CSR build (once, reused by all 3 layers) ----
    k_zero_deg<<<gN, blk, 0, stream>>>(deg);
    k_count<<<gE, blk, 0, stream>>>(ei + N_EDGES, deg);
    k_scan1<<<gScan, blk, 0, stream>>>(deg, row_off, bsums);
    k_scan2<<<1, 128, 0, stream>>>(bsums);
    k_scan3<<<gScan, blk, 0, stream>>>(deg, row_off, cursor, dinv, bsums);
    k_build<<<gE, blk, 0, stream>>>(ei, dinv, cursor, csr_src, csr_w);

    // ---- layer 1: agg(x) -> GEMM(W1)+b1 -> BN1+ReLU ----
    k_aggregate<<<gAgg, blk, 0, stream>>>(x, row_off, deg, csr_src, csr_w, dinv, bufA);
    k_gemm64<<<gRows, blk, 0, stream>>>(bufA, W1, b1, bn1_g, bn1_b, bn1_m, bn1_v, bufB, N_NODES, 2);

    // ---- layer 2 ----
    k_aggregate<<<gAgg, blk, 0, stream>>>(bufB, row_off, deg, csr_src, csr_w, dinv, bufA);
    k_gemm64<<<gRows, blk, 0, stream>>>(bufA, W2, b2, bn2_g, bn2_b, bn2_m, bn2_v, bufB, N_NODES, 2);

    // ---- layer 3 (no BN) ----
    k_aggregate<<<gAgg, blk, 0, stream>>>(bufB, row_off, deg, csr_src, csr_w, dinv, bufA);
    k_gemm64<<<gRows, blk, 0, stream>>>(bufA, W3, b3, nullptr, nullptr, nullptr, nullptr, bufB, N_NODES, 0);

    // ---- predictor MLP: tanh(h@pW1+pb1)@pW2+pb2 ----
    k_gemm64<<<gRows, blk, 0, stream>>>(bufB, pW1, pb1, nullptr, nullptr, nullptr, nullptr, bufA, N_NODES, 1);
    k_gemm64<<<gRows, blk, 0, stream>>>(bufA, pW2, pb2, nullptr, nullptr, nullptr, nullptr, out, N_NODES, 0);
}

// Round 3
// 452.923 us; speedup vs baseline: 4.9863x; 1.1372x over previous
//
#include <hip/hip_runtime.h>

#define N_NODES 100000
#define N_EDGES 800000
#define DIM 64
#define BN_EPS 1e-5f

// ===========================================================================
// CSR build: count in-degrees, exclusive scan, scatter edges grouped by dst.
// Edge payload packed as int2 {src, bits(w)}.
// ===========================================================================

__global__ __launch_bounds__(256) void k_zero_deg(int* __restrict__ deg) {
    int i = blockIdx.x * blockDim.x + threadIdx.x;
    if (i < N_NODES) deg[i] = 0;
}

__global__ __launch_bounds__(256) void k_count(const int* __restrict__ dst,
                                               int* __restrict__ deg) {
    int e = blockIdx.x * blockDim.x + threadIdx.x;
    if (e < N_EDGES) atomicAdd(&deg[dst[e]], 1);
}

// 98 blocks x 256 threads x 4 elems = 100352 >= N. Per-block exclusive scan.
__global__ __launch_bounds__(256) void k_scan1(const int* __restrict__ deg,
                                               int* __restrict__ row_off,
                                               int* __restrict__ block_sums) {
    __shared__ int sdata[256];
    int tid = threadIdx.x;
    int base = blockIdx.x * 1024 + tid * 4;
    int4 v = make_int4(0, 0, 0, 0);
    if (base < N_NODES) v = *(const int4*)(deg + base);   // N % 4 == 0
    int tsum = v.x + v.y + v.z + v.w;
    sdata[tid] = tsum;
    __syncthreads();
    for (int off = 1; off < 256; off <<= 1) {
        int t = (tid >= off) ? sdata[tid - off] : 0;
        __syncthreads();
        sdata[tid] += t;
        __syncthreads();
    }
    int excl = sdata[tid] - tsum;
    if (base < N_NODES) {
        int4 o;
        o.x = excl;
        o.y = o.x + v.x;
        o.z = o.y + v.y;
        o.w = o.z + v.z;
        *(int4*)(row_off + base) = o;
    }
    if (tid == 255) block_sums[blockIdx.x] = sdata[255];
}

__global__ __launch_bounds__(128) void k_scan2(int* __restrict__ block_sums) {
    __shared__ int sdata[128];
    int tid = threadIdx.x;
    int v = (tid < 98) ? block_sums[tid] : 0;
    sdata[tid] = v;
    __syncthreads();
    for (int off = 1; off < 128; off <<= 1) {
        int t = (tid >= off) ? sdata[tid - off] : 0;
        __syncthreads();
        sdata[tid] += t;
        __syncthreads();
    }
    if (tid < 98) block_sums[tid] = sdata[tid] - v;
}

__global__ __launch_bounds__(256) void k_scan3(const int* __restrict__ deg,
                                               int* __restrict__ row_off,
                                               int* __restrict__ cursor,
                                               float* __restrict__ dinv,
                                               const int* __restrict__ block_sums) {
    int tid = threadIdx.x;
    int base = blockIdx.x * 1024 + tid * 4;
    if (base >= N_NODES) return;
    int p = block_sums[blockIdx.x];
    int4 r = *(const int4*)(row_off + base);
    r.x += p; r.y += p; r.z += p; r.w += p;
    *(int4*)(row_off + base) = r;
    *(int4*)(cursor + base) = r;
    int4 d = *(const int4*)(deg + base);
    float4 di;
    di.x = rsqrtf((float)(d.x + 1));
    di.y = rsqrtf((float)(d.y + 1));
    di.z = rsqrtf((float)(d.z + 1));
    di.w = rsqrtf((float)(d.w + 1));
    *(float4*)(dinv + base) = di;
}

__global__ __launch_bounds__(256) void k_build(const int* __restrict__ ei,
                                               const float* __restrict__ dinv,
                                               int* __restrict__ cursor,
                                               int2* __restrict__ edges) {
    int e = blockIdx.x * blockDim.x + threadIdx.x;
    if (e >= N_EDGES) return;
    int s = ei[e];
    int d = ei[N_EDGES + e];
    int pos = atomicAdd(&cursor[d], 1);
    edges[pos] = make_int2(s, __float_as_int(dinv[s] * dinv[d]));
}

// ===========================================================================
// Fused layer: out[n] = epilogue( Agg(x)[n] @ W + bias )
//   Agg(x)[n] = dinv[n]^2 * x[n] + sum_{e: dst=n} w_e * x[src_e]
// Block = 16 nodes. 4 waves gather 4 nodes each (lane = column) into LDS,
// then the block runs a 16x64 @ 64x64 tile matmul with fused epilogue.
// Edge metadata read via wave-uniform (scalar) loads — no shfl, no atomics.
// mode: 0 = bias only, 2 = bias + BN + ReLU
// ===========================================================================
__global__ __launch_bounds__(256) void k_fused_layer(const float* __restrict__ xin,
                                                     const int* __restrict__ row_off,
                                                     const int* __restrict__ deg,
                                                     const int2* __restrict__ edges,
                                                     const float* __restrict__ dinv,
                                                     const float* __restrict__ W,
                                                     const float* __restrict__ bias,
                                                     const float* __restrict__ bng,
                                                     const float* __restrict__ bnb,
                                                     const float* __restrict__ bnm,
                                                     const float* __restrict__ bnv,
                                                     float* __restrict__ out,
                                                     int mode) {
    __shared__ float sW[64][64];
    __shared__ float sAcc[16][65];
    int tid = threadIdx.x;

    // stage W
    for (int i = tid; i < 1024; i += 256)
        ((float4*)&sW[0][0])[i] = ((const float4*)W)[i];

    int lane = tid & 63;
    int wv = tid >> 6;
    int base = blockIdx.x * 16;   // grid = 6250, 6250*16 == N exactly

    for (int nn = 0; nn < 4; ++nn) {
        int node = base + wv * 4 + nn;
        float di = dinv[node];
        float acc = xin[(size_t)node * DIM + lane] * (di * di);
        int beg = __builtin_amdgcn_readfirstlane(row_off[node]);
        int len = __builtin_amdgcn_readfirstlane(deg[node]);
        int end = beg + len;
        int k = beg;
        for (; k + 4 <= end; k += 4) {
            int2 e0 = edges[k];
            int2 e1 = edges[k + 1];
            int2 e2 = edges[k + 2];
            int2 e3 = edges[k + 3];
            float v0 = xin[(size_t)e0.x * DIM + lane];
            float v1 = xin[(size_t)e1.x * DIM + lane];
            float v2 = xin[(size_t)e2.x * DIM + lane];
            float v3 = xin[(size_t)e3.x * DIM + lane];
            acc = fmaf(__int_as_float(e0.y), v0, acc);
            acc = fmaf(__int_as_float(e1.y), v1, acc);
            acc = fmaf(__int_as_float(e2.y), v2, acc);
            acc = fmaf(__int_as_float(e3.y), v3, acc);
        }
        for (; k < end; ++k) {
            int2 e = edges[k];
            acc = fmaf(__int_as_float(e.y), xin[(size_t)e.x * DIM + lane], acc);
        }
        sAcc[wv * 4 + nn][lane] = acc;
    }
    __syncthreads();

    // tile matmul: thread (rl, c4) computes out[row0+rl][c0..c0+3]
    int rl = tid >> 4;
    int c4 = tid & 15;
    int c0 = c4 * 4;
    float4 o = make_float4(0.f, 0.f, 0.f, 0.f);
#pragma unroll
    for (int k = 0; k < 64; k++) {
        float xv = sAcc[rl][k];
        float4 w = *(const float4*)&sW[k][c0];
        o.x += xv * w.x;
        o.y += xv * w.y;
        o.z += xv * w.z;
        o.w += xv * w.w;
    }
    o.x += bias[c0 + 0];
    o.y += bias[c0 + 1];
    o.z += bias[c0 + 2];
    o.w += bias[c0 + 3];
    if (mode == 2) {
        float sx = bng[c0 + 0] * rsqrtf(bnv[c0 + 0] + BN_EPS);
        float sy = bng[c0 + 1] * rsqrtf(bnv[c0 + 1] + BN_EPS);
        float sz = bng[c0 + 2] * rsqrtf(bnv[c0 + 2] + BN_EPS);
        float sw = bng[c0 + 3] * rsqrtf(bnv[c0 + 3] + BN_EPS);
        o.x = fmaxf(0.f, (o.x - bnm[c0 + 0]) * sx + bnb[c0 + 0]);
        o.y = fmaxf(0.f, (o.y - bnm[c0 + 1]) * sy + bnb[c0 + 1]);
        o.z = fmaxf(0.f, (o.z - bnm[c0 + 2]) * sz + bnb[c0 + 2]);
        o.w = fmaxf(0.f, (o.w - bnm[c0 + 3]) * sw + bnb[c0 + 3]);
    }
    ((float4*)(out + (size_t)(base + rl) * DIM))[c4] = o;
}

// ===========================================================================
// Predictor MLP fused: out = tanh(in@W1+b1)@W2+b2, both weights in LDS.
// ===========================================================================
__global__ __launch_bounds__(256) void k_mlp(const float* __restrict__ in,
                                             const float* __restrict__ W1,
                                             const float* __restrict__ b1,
                                             const float* __restrict__ W2,
                                             const float* __restrict__ b2,
                                             float* __restrict__ out) {
    __shared__ float sW1[64][64];
    __shared__ float sW2[64][64];
    __shared__ float sX[16][65];
    int tid = threadIdx.x;

    for (int i = tid; i < 1024; i += 256) {
        ((float4*)&sW1[0][0])[i] = ((const float4*)W1)[i];
        ((float4*)&sW2[0][0])[i] = ((const float4*)W2)[i];
    }

    int row0 = blockIdx.x * 16;
    int rl = tid >> 4;
    int c4 = tid & 15;
    int c0 = c4 * 4;

    {
        float4 v = ((const float4*)(in + (size_t)(row0 + rl) * DIM))[c4];
        sX[rl][c0 + 0] = v.x;
        sX[rl][c0 + 1] = v.y;
        sX[rl][c0 + 2] = v.z;
        sX[rl][c0 + 3] = v.w;
    }
    __syncthreads();

    float4 t = make_float4(0.f, 0.f, 0.f, 0.f);
#pragma unroll
    for (int k = 0; k < 64; k++) {
        float xv = sX[rl][k];
        float4 w = *(const float4*)&sW1[k][c0];
        t.x += xv * w.x;
        t.y += xv * w.y;
        t.z += xv * w.z;
        t.w += xv * w.w;
    }
    t.x = tanhf(t.x + b1[c0 + 0]);
    t.y = tanhf(t.y + b1[c0 + 1]);
    t.z = tanhf(t.z + b1[c0 + 2]);
    t.w = tanhf(t.w + b1[c0 + 3]);
    __syncthreads();   // everyone done reading sX
    sX[rl][c0 + 0] = t.x;
    sX[rl][c0 + 1] = t.y;
    sX[rl][c0 + 2] = t.z;
    sX[rl][c0 + 3] = t.w;
    __syncthreads();

    float4 o = make_float4(0.f, 0.f, 0.f, 0.f);
#pragma unroll
    for (int k = 0; k < 64; k++) {
        float xv = sX[rl][k];
        float4 w = *(const float4*)&sW2[k][c0];
        o.x += xv * w.x;
        o.y += xv * w.y;
        o.z += xv * w.z;
        o.w += xv * w.w;
    }
    o.x += b2[c0 + 0];
    o.y += b2[c0 + 1];
    o.z += b2[c0 + 2];
    o.w += b2[c0 + 3];
    ((float4*)(out + (size_t)(row0 + rl) * DIM))[c4] = o;
}

// ===========================================================================
extern "C" void kernel_launch(void* const* d_in, const int* in_sizes, int n_in,
                              void* d_out, int out_size, void* d_ws, size_t ws_size,
                              hipStream_t stream) {
    const float* x     = (const float*)d_in[0];
    const int*   ei    = (const int*)d_in[1];
    const float* W1    = (const float*)d_in[2];
    const float* b1    = (const float*)d_in[3];
    const float* W2    = (const float*)d_in[4];
    const float* b2    = (const float*)d_in[5];
    const float* W3    = (const float*)d_in[6];
    const float* b3    = (const float*)d_in[7];
    const float* bn1_g = (const float*)d_in[8];
    const float* bn1_b = (const float*)d_in[9];
    const float* bn1_m = (const float*)d_in[10];
    const float* bn1_v = (const float*)d_in[11];
    const float* bn2_g = (const float*)d_in[12];
    const float* bn2_b = (const float*)d_in[13];
    const float* bn2_m = (const float*)d_in[14];
    const float* bn2_v = (const float*)d_in[15];
    const float* pW1   = (const float*)d_in[16];
    const float* pb1   = (const float*)d_in[17];
    const float* pW2   = (const float*)d_in[18];
    const float* pb2   = (const float*)d_in[19];
    float* out = (float*)d_out;

    char* ws = (char*)d_ws;
    int*   deg      = (int*)ws;                      ws += 100352 * 4;
    int*   row_off  = (int*)ws;                      ws += 100352 * 4;
    int*   cursor   = (int*)ws;                      ws += 100352 * 4;
    int*   bsums    = (int*)ws;                      ws += 128 * 4;
    int2*  edges    = (int2*)ws;                     ws += (size_t)N_EDGES * 8;
    float* dinv     = (float*)ws;                    ws += 100352 * 4;
    float* bufA     = (float*)ws;                    ws += (size_t)N_NODES * DIM * 4;
    float* bufB     = (float*)ws;

    const int blk = 256;
    int gN     = (N_NODES + blk - 1) / blk;      // 391
    int gE     = (N_EDGES + blk - 1) / blk;      // 3125
    int gScan  = 98;
    int gTiles = N_NODES / 16;                   // 6250 (N divisible by 16)

    // ---- CSR build (once, reused by all 3 layers) ----
    k_zero_deg<<<gN, blk, 0, stream>>>(deg);
    k_count<<<gE, blk, 0, stream>>>(ei + N_EDGES, deg);
    k_scan1<<<gScan, blk, 0, stream>>>(deg, row_off, bsums);
    k_scan2<<<1, 128, 0, stream>>>(bsums);
    k_scan3<<<gScan, blk, 0, stream>>>(deg, row_off, cursor, dinv, bsums);
    k_build<<<gE, blk, 0, stream>>>(ei, dinv, cursor, edges);

    // ---- 3 fused GCN layers ----
    k_fused_layer<<<gTiles, blk, 0, stream>>>(x, row_off, deg, edges, dinv,
                                              W1, b1, bn1_g, bn1_b, bn1_m, bn1_v, bufA, 2);
    k_fused_layer<<<gTiles, blk, 0, stream>>>(bufA, row_off, deg, edges, dinv,
                                              W2, b2, bn2_g, bn2_b, bn2_m, bn2_v, bufB, 2);
    k_fused_layer<<<gTiles, blk, 0, stream>>>(bufB, row_off, deg, edges, dinv,
                                              W3, b3, nullptr, nullptr, nullptr, nullptr, bufA, 0);

    // ---- predictor MLP ----
    k_mlp<<<gTiles, blk, 0, stream>>>(bufA, pW1, pb1, pW2, pb2, out);
}